// Round 2
// baseline (3630.654 us; speedup 1.0000x reference)
//
#include <hip/hip_runtime.h>
#include <hip/hip_bf16.h>
#include <math.h>

#define HID 192
#define NNODES 5184
#define NSTEPS 16

typedef float f32x4 __attribute__((ext_vector_type(4)));
typedef __bf16 bf16x8 __attribute__((ext_vector_type(8)));
typedef unsigned short ushort_t;
typedef ushort_t us8 __attribute__((ext_vector_type(8)));

__device__ __forceinline__ ushort_t f2bf(float f){
    __hip_bfloat16 h = __float2bfloat16(f);
    return __builtin_bit_cast(ushort_t, h);
}
__device__ __forceinline__ float bf2f(ushort_t u){
    return __uint_as_float(((unsigned)u) << 16);
}

// swizzled index helpers (bank-conflict-free fragment reads)
#define HFI(r,c) ((r)*192 + ((c) ^ (((r)&7)<<2)))   // f32 buffer [81][192]
#define ABI(r,c) ((r)*384 + ((c) ^ (((r)&7)<<3)))   // bf16 buffer [81][384]
#define HBI(r,c) ((r)*192 + ((c) ^ (((r)&7)<<3)))   // bf16 buffer [81][192]

// load MFMA A-fragment (16x32 bf16) from a [81][192] bf16 LDS buffer (HBI swizzle)
__device__ __forceinline__ bf16x8 ldsfrag(const ushort_t* buf, int rt, int ks, int lane){
    int r = rt*16 + (lane & 15);
    int k0 = ks*32 + ((lane >> 4) << 3);
    if (r < 81) return *(const bf16x8*)&buf[HBI(r, k0)];
    us8 z = {0,0,0,0,0,0,0,0};
    return __builtin_bit_cast(bf16x8, z);
}
// load MFMA B-fragment from pre-permuted weight array
__device__ __forceinline__ bf16x8 wfrag(const ushort_t* W, int ct, int ks, int lane){
    return *(const bf16x8*)&W[(size_t)(((ct*6) + ks)*64 + lane)*8];
}

// ---------------------------------------------------------------------------
// fp32 tiled GEMM (round-1, verified) -- used once for Wfused = W_m2 @ W_ih^T
// ---------------------------------------------------------------------------
template <bool TRANSB>
__global__ __launch_bounds__(256)
void k_gemm(const float* __restrict__ A, const float* __restrict__ B,
            const float* __restrict__ bias, float biasScale,
            float* __restrict__ C, int N) {
    const int K = HID;
    __shared__ float As[64][17];
    __shared__ float Bs[16][65];
    int tid = threadIdx.x;
    int tx = tid & 15, ty = tid >> 4;
    int rowBase = blockIdx.x * 64;
    int colBase = blockIdx.y * 64;
    float acc[4][4] = {};
    for (int k0 = 0; k0 < K; k0 += 16) {
        {
            int r = tid >> 2, kk = (tid & 3) << 2;
            const float4 av = *(const float4*)&A[(size_t)(rowBase + r) * K + k0 + kk];
            As[r][kk + 0] = av.x; As[r][kk + 1] = av.y;
            As[r][kk + 2] = av.z; As[r][kk + 3] = av.w;
        }
        if (!TRANSB) {
            int kk = tid >> 4, j4 = (tid & 15) << 2;
            const float4 bv = *(const float4*)&B[(size_t)(k0 + kk) * N + colBase + j4];
            Bs[kk][j4 + 0] = bv.x; Bs[kk][j4 + 1] = bv.y;
            Bs[kk][j4 + 2] = bv.z; Bs[kk][j4 + 3] = bv.w;
        } else {
            int jj = tid >> 2, kk = (tid & 3) << 2;
            const float4 bv = *(const float4*)&B[(size_t)(colBase + jj) * K + k0 + kk];
            Bs[kk + 0][jj] = bv.x; Bs[kk + 1][jj] = bv.y;
            Bs[kk + 2][jj] = bv.z; Bs[kk + 3][jj] = bv.w;
        }
        __syncthreads();
#pragma unroll
        for (int kk = 0; kk < 16; kk++) {
            float a0 = As[ty*4+0][kk], a1 = As[ty*4+1][kk];
            float a2 = As[ty*4+2][kk], a3 = As[ty*4+3][kk];
            float b0 = Bs[kk][tx*4+0], b1 = Bs[kk][tx*4+1];
            float b2 = Bs[kk][tx*4+2], b3 = Bs[kk][tx*4+3];
            acc[0][0]+=a0*b0; acc[0][1]+=a0*b1; acc[0][2]+=a0*b2; acc[0][3]+=a0*b3;
            acc[1][0]+=a1*b0; acc[1][1]+=a1*b1; acc[1][2]+=a1*b2; acc[1][3]+=a1*b3;
            acc[2][0]+=a2*b0; acc[2][1]+=a2*b1; acc[2][2]+=a2*b2; acc[2][3]+=a2*b3;
            acc[3][0]+=a3*b0; acc[3][1]+=a3*b1; acc[3][2]+=a3*b2; acc[3][3]+=a3*b3;
        }
        __syncthreads();
    }
    float4 bb = make_float4(0.f,0.f,0.f,0.f);
    if (bias) {
        bb = *(const float4*)&bias[colBase + tx*4];
        bb.x*=biasScale; bb.y*=biasScale; bb.z*=biasScale; bb.w*=biasScale;
    }
#pragma unroll
    for (int i = 0; i < 4; i++) {
        int r = rowBase + ty*4 + i;
        float4 o;
        o.x=acc[i][0]+bb.x; o.y=acc[i][1]+bb.y; o.z=acc[i][2]+bb.z; o.w=acc[i][3]+bb.w;
        *(float4*)&C[(size_t)r * N + colBase + tx*4] = o;
    }
}

// ---------------------------------------------------------------------------
// prep: convert weights to bf16 MFMA B-fragment layout + fused bias
// fragIdx(ct,ks,lane,e): value = W[k = ks*32+8*(lane>>4)+e][col = ct*16+(lane&15)]
// ---------------------------------------------------------------------------
__global__ void k_prep(const float* __restrict__ W_m1, const float* __restrict__ Wfused,
                       const float* __restrict__ W_hh, const float* __restrict__ W_out,
                       const float* __restrict__ W_ih, const float* __restrict__ b_m2,
                       const float* __restrict__ b_ih,
                       ushort_t* __restrict__ Wm1b, ushort_t* __restrict__ W2ihb,
                       ushort_t* __restrict__ Whhb, ushort_t* __restrict__ Woutb,
                       float* __restrict__ bias_f) {
    int t = blockIdx.x * 256 + threadIdx.x;
    const int n0 = 73728, n1 = n0 + 110592, n2 = n1 + 110592, n3 = n2 + 3072, n4 = n3 + 576;
    if (t < n0) {
        int idx = t;
        int e = idx & 7, lane = (idx >> 3) & 63, cs = idx >> 9;
        int ct = cs / 6, ks = cs - ct*6;
        int k = ks*32 + ((lane>>4)<<3) + e, col = ct*16 + (lane & 15);
        float v = (col < 192) ? W_m1[k*192 + col] : W_m1[(192 + k)*192 + (col - 192)];
        Wm1b[idx] = f2bf(v);
    } else if (t < n1) {
        int idx = t - n0;
        int e = idx & 7, lane = (idx >> 3) & 63, cs = idx >> 9;
        int ct = cs / 6, ks = cs - ct*6;
        int k = ks*32 + ((lane>>4)<<3) + e, col = ct*16 + (lane & 15);
        W2ihb[idx] = f2bf(Wfused[k*576 + col]);
    } else if (t < n2) {
        int idx = t - n1;
        int e = idx & 7, lane = (idx >> 3) & 63, cs = idx >> 9;
        int ct = cs / 6, ks = cs - ct*6;
        int k = ks*32 + ((lane>>4)<<3) + e, col = ct*16 + (lane & 15);
        Whhb[idx] = f2bf(W_hh[col*192 + k]);   // W_hh^T[k][col]
    } else if (t < n3) {
        int idx = t - n2;
        int e = idx & 7, lane = (idx >> 3) & 63, ks = idx >> 9;
        int k = ks*32 + ((lane>>4)<<3) + e, col = lane & 15;
        Woutb[idx] = (col < 9) ? f2bf(W_out[k*9 + col]) : (ushort_t)0;
    } else if (t < n4) {
        int n = t - n3;
        float s = 0.f;
        for (int m = 0; m < 192; m++) s += b_m2[m] * W_ih[n*192 + m];
        bias_f[n] = 20.f * s + b_ih[n];
    }
}

// ---------------------------------------------------------------------------
// Monolithic RRN kernel: one workgroup per graph, all 16 steps LDS-resident.
// LDS map (158592 B total):
//   hf   f32  [81][192] @0       (hc scratch, HFI swizzle)
//   AB   bf16 [81][384] @62208   (A|B proj; Rb and x-staging overlay)
//   hb   bf16 [81][192] @124416  (h state, HBI swizzle)
//   ssum/ssq f32[96]    @155520/155904
//   bm1s/gns/bens f32[192] @156288/157056/157824
// ---------------------------------------------------------------------------
__global__ __launch_bounds__(512, 2)
void k_main(const float* __restrict__ x, const float* __restrict__ W_in,
            const float* __restrict__ b_in, const float* __restrict__ g_in,
            const float* __restrict__ be_in, const float* __restrict__ pos,
            const float* __restrict__ b_m1, const float* __restrict__ g_n,
            const float* __restrict__ be_n, const float* __restrict__ b_hh,
            const float* __restrict__ b_out,
            const ushort_t* __restrict__ Wm1b, const ushort_t* __restrict__ W2ihb,
            const ushort_t* __restrict__ Whhb, const ushort_t* __restrict__ Woutb,
            const float* __restrict__ bias_f,
            float* __restrict__ out_all, float* __restrict__ out_last)
{
    extern __shared__ char smem[];
    float*    hf  = (float*)(smem);
    ushort_t* AB  = (ushort_t*)(smem + 62208);
    ushort_t* hb  = (ushort_t*)(smem + 124416);
    float* ssum = (float*)(smem + 155520);
    float* ssq  = (float*)(smem + 155904);
    float* bm1s = (float*)(smem + 156288);
    float* gns  = (float*)(smem + 157056);
    float* bens = (float*)(smem + 157824);

    const int tid = threadIdx.x;
    const int lane = tid & 63, wave = tid >> 6;
    const int l15 = lane & 15, q4 = (lane >> 4) << 2;
    const int g = blockIdx.x;

    if (tid < 192) { bm1s[tid] = b_m1[tid]; gns[tid] = g_n[tid]; bens[tid] = be_n[tid]; }

    // ---------------- h0 = LN(x@W_in + b_in)*g+be + pos ----------------
    {
        float* xs = (float*)AB;
        for (int e = tid; e < 810; e += 512) xs[e] = x[(size_t)g*810 + e];
        __syncthreads();
        for (int e = tid; e < 15552; e += 512) {
            int n = e / 192, j = e - n*192;
            float v = b_in[j];
#pragma unroll
            for (int k = 0; k < 10; k++) v += xs[n*10 + k] * W_in[k*192 + j];
            hf[HFI(n, j)] = v;
        }
        __syncthreads();
        if (tid < 81) {
            float s = 0.f, sq = 0.f;
            for (int c = 0; c < 192; c++) { float v = hf[HFI(tid, c)]; s += v; sq += v*v; }
            float m = s * (1.f/192.f);
            float var = sq * (1.f/192.f) - m*m;
            ssum[tid] = m; ssq[tid] = rsqrtf(var + 1e-5f);
        }
        __syncthreads();
        for (int e = tid; e < 15552; e += 512) {
            int n = e / 192, j = e - n*192;
            float v = hf[HFI(n, j)];
            v = (v - ssum[n]) * ssq[n] * g_in[j] + be_in[j] + pos[n*192 + j];
            hb[HBI(n, j)] = f2bf(v);
        }
        __syncthreads();
    }

    for (int t = 0; t < NSTEPS; t++) {
        // ===== Phase A: [A|B] = h @ Wm1comb  (b_m1 folded into B half) =====
        {
            bf16x8 wb[3][6];
#pragma unroll
            for (int c = 0; c < 3; c++)
#pragma unroll
                for (int ks = 0; ks < 6; ks++)
                    wb[c][ks] = wfrag(Wm1b, wave*3 + c, ks, lane);
#pragma unroll
            for (int rt = 0; rt < 6; rt++) {
                bf16x8 ha[6];
#pragma unroll
                for (int ks = 0; ks < 6; ks++) ha[ks] = ldsfrag(hb, rt, ks, lane);
#pragma unroll
                for (int c = 0; c < 3; c++) {
                    f32x4 acc = {0.f, 0.f, 0.f, 0.f};
#pragma unroll
                    for (int ks = 0; ks < 6; ks++)
                        acc = __builtin_amdgcn_mfma_f32_16x16x32_bf16(ha[ks], wb[c][ks], acc, 0, 0, 0);
                    int col = (wave*3 + c)*16 + l15;
                    float addb = (col >= 192) ? bm1s[col - 192] : 0.f;
#pragma unroll
                    for (int i2 = 0; i2 < 4; i2++) {
                        int row = rt*16 + q4 + i2;
                        if (row < 81) AB[ABI(row, col)] = f2bf(acc[i2] + addb);
                    }
                }
            }
        }
        __syncthreads();   // SYNC1

        // ===== Phase B: R[d] = sum_{s in nbr(d)} relu(A[s] + B[d]) =====
        float racc[4][8];
#pragma unroll
        for (int it = 0; it < 4; it++) {
            int e = tid + 512*it;
            if (e < 1944) {
                int d = e / 24, j8 = e - d*24;
                int j0 = j8 * 8;
                float bsum[8], r8[8] = {0,0,0,0,0,0,0,0};
                us8 bu = *(const us8*)&AB[ABI(d, 192 + j0)];
#pragma unroll
                for (int i = 0; i < 8; i++) bsum[i] = bf2f(bu[i]);
                int rr = d / 9, cc = d - rr*9;
                int rb0 = (rr/3)*3, cb0 = (cc/3)*3;
#pragma unroll
                for (int c2 = 0; c2 < 9; c2++) {
                    if (c2 == cc) continue;
                    us8 au = *(const us8*)&AB[ABI(rr*9 + c2, j0)];
#pragma unroll
                    for (int i = 0; i < 8; i++) r8[i] += fmaxf(bf2f(au[i]) + bsum[i], 0.f);
                }
#pragma unroll
                for (int r2 = 0; r2 < 9; r2++) {
                    if (r2 == rr) continue;
                    us8 au = *(const us8*)&AB[ABI(r2*9 + cc, j0)];
#pragma unroll
                    for (int i = 0; i < 8; i++) r8[i] += fmaxf(bf2f(au[i]) + bsum[i], 0.f);
                }
#pragma unroll
                for (int r2 = 0; r2 < 3; r2++) {
                    int rrr = rb0 + r2;
                    if (rrr == rr) continue;
#pragma unroll
                    for (int c2 = 0; c2 < 3; c2++) {
                        int ccc = cb0 + c2;
                        if (ccc == cc) continue;
                        us8 au = *(const us8*)&AB[ABI(rrr*9 + ccc, j0)];
#pragma unroll
                        for (int i = 0; i < 8; i++) r8[i] += fmaxf(bf2f(au[i]) + bsum[i], 0.f);
                    }
                }
#pragma unroll
                for (int i = 0; i < 8; i++) racc[it][i] = r8[i];
            }
        }
        __syncthreads();   // SYNC2
        if (tid < 96) { ssum[tid] = 0.f; ssq[tid] = 0.f; }
#pragma unroll
        for (int it = 0; it < 4; it++) {
            int e = tid + 512*it;
            if (e < 1944) {
                int d = e / 24, j8 = e - d*24;
                int j0 = j8 * 8;
                us8 w;
#pragma unroll
                for (int i = 0; i < 8; i++) w[i] = f2bf(racc[it][i]);
                *(us8*)&AB[HBI(d, j0)] = w;   // Rb overlays AB, HBI geometry
            }
        }
        __syncthreads();   // SYNC3

        // ===== Phase C: gates (2 GEMMs) + GRU -> hc into hf =====
        {
            bf16x8 bfr[6][6];
            const int u0 = wave * 9;
#pragma unroll
            for (int uu = 0; uu < 9; uu++) {
                int u = u0 + uu;
                int jt = u / 6, rt = u - jt*6;
                if (uu == 0 || rt == 0) {
#pragma unroll
                    for (int ks = 0; ks < 6; ks++) {
                        bfr[0][ks] = wfrag(W2ihb, jt,      ks, lane);
                        bfr[1][ks] = wfrag(W2ihb, jt + 12, ks, lane);
                        bfr[2][ks] = wfrag(W2ihb, jt + 24, ks, lane);
                        bfr[3][ks] = wfrag(Whhb,  jt,      ks, lane);
                        bfr[4][ks] = wfrag(Whhb,  jt + 12, ks, lane);
                        bfr[5][ks] = wfrag(Whhb,  jt + 24, ks, lane);
                    }
                }
                f32x4 a0={0,0,0,0}, a1={0,0,0,0}, a2={0,0,0,0};
                f32x4 a3={0,0,0,0}, a4={0,0,0,0}, a5={0,0,0,0};
#pragma unroll
                for (int ks = 0; ks < 6; ks++) {
                    bf16x8 ra = ldsfrag(AB, rt, ks, lane);
                    bf16x8 ha = ldsfrag(hb, rt, ks, lane);
                    a0 = __builtin_amdgcn_mfma_f32_16x16x32_bf16(ra, bfr[0][ks], a0, 0,0,0);
                    a1 = __builtin_amdgcn_mfma_f32_16x16x32_bf16(ra, bfr[1][ks], a1, 0,0,0);
                    a2 = __builtin_amdgcn_mfma_f32_16x16x32_bf16(ra, bfr[2][ks], a2, 0,0,0);
                    a3 = __builtin_amdgcn_mfma_f32_16x16x32_bf16(ha, bfr[3][ks], a3, 0,0,0);
                    a4 = __builtin_amdgcn_mfma_f32_16x16x32_bf16(ha, bfr[4][ks], a4, 0,0,0);
                    a5 = __builtin_amdgcn_mfma_f32_16x16x32_bf16(ha, bfr[5][ks], a5, 0,0,0);
                }
                int col = jt*16 + l15;
                float bi_r = bias_f[col], bi_z = bias_f[col+192], bi_n = bias_f[col+384];
                float bh_r = b_hh[col],   bh_z = b_hh[col+192],   bh_n = b_hh[col+384];
#pragma unroll
                for (int i2 = 0; i2 < 4; i2++) {
                    int row = rt*16 + q4 + i2;
                    float ir = a0[i2]+bi_r, iz = a1[i2]+bi_z, inn = a2[i2]+bi_n;
                    float hr = a3[i2]+bh_r, hz = a4[i2]+bh_z, hn  = a5[i2]+bh_n;
                    float hv = (row < 81) ? bf2f(hb[HBI(row, col)]) : 0.f;
                    float rg = 1.f/(1.f + __expf(-(ir + hr)));
                    float zg = 1.f/(1.f + __expf(-(iz + hz)));
                    float e2 = __expf(2.f*(inn + rg*hn));
                    float ng = 1.f - 2.f/(e2 + 1.f);
                    float hc = (1.f - zg)*ng + zg*hv;
                    if (row < 81) hf[HFI(row, col)] = hc;
                    float s = hc, sq2 = hc*hc;
#pragma unroll
                    for (int m = 1; m < 16; m <<= 1) {
                        s   += __shfl_xor(s, m);
                        sq2 += __shfl_xor(sq2, m);
                    }
                    if (l15 == 0 && row < 81) { atomicAdd(&ssum[row], s); atomicAdd(&ssq[row], sq2); }
                }
            }
        }
        __syncthreads();   // SYNC4
        if (tid < 81) {
            float m = ssum[tid] * (1.f/192.f);
            float var = ssq[tid] * (1.f/192.f) - m*m;
            ssum[tid] = m; ssq[tid] = rsqrtf(var + 1e-5f);
        }
        __syncthreads();   // SYNC5
        // ===== Phase D: LayerNorm -> new h (bf16) =====
        for (int e = tid; e < 15552; e += 512) {
            int n = e / 192, j = e - n*192;
            float hc = hf[HFI(n, j)];
            float hn2 = (hc - ssum[n]) * ssq[n] * gns[j] + bens[j];
            hb[HBI(n, j)] = f2bf(hn2);
        }
        __syncthreads();   // SYNC6
        // ===== Phase E: logits = h @ W_out + b_out =====
        if (wave < 6) {
            int rt = wave;
            f32x4 acc = {0.f, 0.f, 0.f, 0.f};
#pragma unroll
            for (int ks = 0; ks < 6; ks++) {
                bf16x8 ha = ldsfrag(hb, rt, ks, lane);
                acc = __builtin_amdgcn_mfma_f32_16x16x32_bf16(ha, wfrag(Woutb, 0, ks, lane), acc, 0,0,0);
            }
            if (l15 < 9) {
                float bo = b_out[l15];
#pragma unroll
                for (int i2 = 0; i2 < 4; i2++) {
                    int row = rt*16 + q4 + i2;
                    if (row < 81) {
                        float v = acc[i2] + bo;
                        out_all[((size_t)t*NNODES + (size_t)g*81 + row)*9 + l15] = v;
                        if (t == NSTEPS-1)
                            out_last[((size_t)g*81 + row)*9 + l15] = v;
                    }
                }
            }
        }
    }
}

// ---------------------------------------------------------------------------
extern "C" void kernel_launch(void* const* d_in, const int* in_sizes, int n_in,
                              void* d_out, int out_size, void* d_ws, size_t ws_size,
                              hipStream_t stream) {
    const float* x     = (const float*)d_in[0];
    const float* W_in  = (const float*)d_in[2];
    const float* b_in  = (const float*)d_in[3];
    const float* g_in  = (const float*)d_in[4];
    const float* be_in = (const float*)d_in[5];
    const float* pos   = (const float*)d_in[6];
    const float* W_m1  = (const float*)d_in[7];
    const float* b_m1  = (const float*)d_in[8];
    const float* W_m2  = (const float*)d_in[9];
    const float* b_m2  = (const float*)d_in[10];
    const float* W_ih  = (const float*)d_in[11];
    const float* W_hh  = (const float*)d_in[12];
    const float* b_ih  = (const float*)d_in[13];
    const float* b_hh  = (const float*)d_in[14];
    const float* g_n   = (const float*)d_in[15];
    const float* be_n  = (const float*)d_in[16];
    const float* W_out = (const float*)d_in[17];
    const float* b_out = (const float*)d_in[18];

    char* ws = (char*)d_ws;
    float*    Wfused = (float*)ws;                   // 192*576*4 = 442368
    ushort_t* Wm1b   = (ushort_t*)(ws + 442368);     // 147456
    ushort_t* W2ihb  = (ushort_t*)(ws + 589824);     // 221184
    ushort_t* Whhb   = (ushort_t*)(ws + 811008);     // 221184
    ushort_t* Woutb  = (ushort_t*)(ws + 1032192);    // 6144
    float*    bias_f = (float*)(ws + 1038336);       // 2304

    float* out_last = (float*)d_out;                 // (5184, 9)
    float* out_all  = (float*)d_out + NNODES*9;      // (16, 5184, 9)

    // Wfused = W_m2 @ W_ih^T   (192 x 576, fp32)
    k_gemm<true><<<dim3(3, 9), 256, 0, stream>>>(W_m2, W_ih, nullptr, 0.f, Wfused, 576);
    // weight -> bf16 fragment layout + fused bias
    k_prep<<<(298560 + 255)/256, 256, 0, stream>>>(W_m1, Wfused, W_hh, W_out, W_ih, b_m2, b_ih,
                                                   Wm1b, W2ihb, Whhb, Woutb, bias_f);

    const int LDS_BYTES = 158592;
    hipFuncSetAttribute(reinterpret_cast<const void*>(k_main),
                        hipFuncAttributeMaxDynamicSharedMemorySize, LDS_BYTES);
    k_main<<<64, 512, LDS_BYTES, stream>>>(x, W_in, b_in, g_in, be_in, pos, b_m1, g_n, be_n,
                                           b_hh, b_out, Wm1b, W2ihb, Whhb, Woutb, bias_f,
                                           out_all, out_last);
}

// Round 3
// 2090.420 us; speedup vs baseline: 1.7368x; 1.7368x over previous
//
#include <hip/hip_runtime.h>
#include <hip/hip_bf16.h>
#include <math.h>

#define HID 192
#define NNODES 5184
#define NSTEPS 16

typedef float f32x4 __attribute__((ext_vector_type(4)));
typedef __bf16 bf16x8 __attribute__((ext_vector_type(8)));
typedef unsigned short ushort_t;
typedef ushort_t us8 __attribute__((ext_vector_type(8)));

__device__ __forceinline__ ushort_t f2bf(float f){
    __hip_bfloat16 h = __float2bfloat16(f);
    return __builtin_bit_cast(ushort_t, h);
}
__device__ __forceinline__ float bf2f(ushort_t u){
    return __uint_as_float(((unsigned)u) << 16);
}

// swizzled index helpers (bank-conflict-free fragment reads)
#define HFI(r,c) ((r)*192 + ((c) ^ (((r)&7)<<2)))   // f32 buffer [81][192]
#define ABI(r,c) ((r)*384 + ((c) ^ (((r)&7)<<3)))   // bf16 buffer [81][384]
#define HBI(r,c) ((r)*192 + ((c) ^ (((r)&7)<<3)))   // bf16 buffer [81][192]

// load MFMA A-fragment (16x32 bf16) from a [81][192] bf16 LDS buffer (HBI swizzle)
__device__ __forceinline__ bf16x8 ldsfrag(const ushort_t* buf, int rt, int ks, int lane){
    int r = rt*16 + (lane & 15);
    int k0 = ks*32 + ((lane >> 4) << 3);
    if (r < 81) return *(const bf16x8*)&buf[HBI(r, k0)];
    us8 z = {0,0,0,0,0,0,0,0};
    return __builtin_bit_cast(bf16x8, z);
}
// pre-permuted weight fragment: array of [ct][nks][64][8]
__device__ __forceinline__ bf16x8 wfragN(const ushort_t* W, int ct, int nks, int ks, int lane){
    return *(const bf16x8*)&W[(size_t)(((ct*nks) + ks)*64 + lane)*8];
}

// ---------------------------------------------------------------------------
// fp32 tiled GEMM -- used once for Wfused = W_m2 @ W_ih^T
// ---------------------------------------------------------------------------
template <bool TRANSB>
__global__ __launch_bounds__(256)
void k_gemm(const float* __restrict__ A, const float* __restrict__ B,
            const float* __restrict__ bias, float biasScale,
            float* __restrict__ C, int N) {
    const int K = HID;
    __shared__ float As[64][17];
    __shared__ float Bs[16][65];
    int tid = threadIdx.x;
    int tx = tid & 15, ty = tid >> 4;
    int rowBase = blockIdx.x * 64;
    int colBase = blockIdx.y * 64;
    float acc[4][4] = {};
    for (int k0 = 0; k0 < K; k0 += 16) {
        {
            int r = tid >> 2, kk = (tid & 3) << 2;
            const float4 av = *(const float4*)&A[(size_t)(rowBase + r) * K + k0 + kk];
            As[r][kk + 0] = av.x; As[r][kk + 1] = av.y;
            As[r][kk + 2] = av.z; As[r][kk + 3] = av.w;
        }
        if (!TRANSB) {
            int kk = tid >> 4, j4 = (tid & 15) << 2;
            const float4 bv = *(const float4*)&B[(size_t)(k0 + kk) * N + colBase + j4];
            Bs[kk][j4 + 0] = bv.x; Bs[kk][j4 + 1] = bv.y;
            Bs[kk][j4 + 2] = bv.z; Bs[kk][j4 + 3] = bv.w;
        } else {
            int jj = tid >> 2, kk = (tid & 3) << 2;
            const float4 bv = *(const float4*)&B[(size_t)(colBase + jj) * K + k0 + kk];
            Bs[kk + 0][jj] = bv.x; Bs[kk + 1][jj] = bv.y;
            Bs[kk + 2][jj] = bv.z; Bs[kk + 3][jj] = bv.w;
        }
        __syncthreads();
#pragma unroll
        for (int kk = 0; kk < 16; kk++) {
            float a0 = As[ty*4+0][kk], a1 = As[ty*4+1][kk];
            float a2 = As[ty*4+2][kk], a3 = As[ty*4+3][kk];
            float b0 = Bs[kk][tx*4+0], b1 = Bs[kk][tx*4+1];
            float b2 = Bs[kk][tx*4+2], b3 = Bs[kk][tx*4+3];
            acc[0][0]+=a0*b0; acc[0][1]+=a0*b1; acc[0][2]+=a0*b2; acc[0][3]+=a0*b3;
            acc[1][0]+=a1*b0; acc[1][1]+=a1*b1; acc[1][2]+=a1*b2; acc[1][3]+=a1*b3;
            acc[2][0]+=a2*b0; acc[2][1]+=a2*b1; acc[2][2]+=a2*b2; acc[2][3]+=a2*b3;
            acc[3][0]+=a3*b0; acc[3][1]+=a3*b1; acc[3][2]+=a3*b2; acc[3][3]+=a3*b3;
        }
        __syncthreads();
    }
    float4 bb = make_float4(0.f,0.f,0.f,0.f);
    if (bias) {
        bb = *(const float4*)&bias[colBase + tx*4];
        bb.x*=biasScale; bb.y*=biasScale; bb.z*=biasScale; bb.w*=biasScale;
    }
#pragma unroll
    for (int i = 0; i < 4; i++) {
        int r = rowBase + ty*4 + i;
        float4 o;
        o.x=acc[i][0]+bb.x; o.y=acc[i][1]+bb.y; o.z=acc[i][2]+bb.z; o.w=acc[i][3]+bb.w;
        *(float4*)&C[(size_t)r * N + colBase + tx*4] = o;
    }
}

// ---------------------------------------------------------------------------
// prep: permute weights into MFMA B-fragment layouts.
// frag value = W[k = ks*32 + 8*(lane>>4) + e][col = ct*16 + (lane&15)]
// Gate-stacked layouts (K=384: k<192 from Wfused, k>=192 from W_hh^T):
//   Wr : S_r weights, Wz : S_z weights, Wni : inn (K=192), Wnh : hn (K=192)
// ---------------------------------------------------------------------------
__global__ void k_prep(const float* __restrict__ W_m1, const float* __restrict__ Wfused,
                       const float* __restrict__ W_hh, const float* __restrict__ W_out,
                       const float* __restrict__ W_ih, const float* __restrict__ b_m2,
                       const float* __restrict__ b_ih,
                       ushort_t* __restrict__ Wm1b, ushort_t* __restrict__ Wr,
                       ushort_t* __restrict__ Wz, ushort_t* __restrict__ Wni,
                       ushort_t* __restrict__ Wnh, ushort_t* __restrict__ Woutb,
                       float* __restrict__ bias_f) {
    int t = blockIdx.x * 256 + threadIdx.x;
    const int n0 = 73728;            // Wm1b
    const int n1 = n0 + 73728;       // Wr
    const int n2 = n1 + 73728;       // Wz
    const int n3 = n2 + 36864;       // Wni
    const int n4 = n3 + 36864;       // Wnh
    const int n5 = n4 + 3072;        // Woutb
    const int n6 = n5 + 576;         // bias_f
    if (t < n0) {
        int idx = t;
        int e = idx & 7, lane = (idx >> 3) & 63, cs = idx >> 9;
        int ct = cs / 6, ks = cs - ct*6;
        int k = ks*32 + ((lane>>4)<<3) + e, col = ct*16 + (lane & 15);
        float v = (col < 192) ? W_m1[k*192 + col] : W_m1[(192 + k)*192 + (col - 192)];
        Wm1b[idx] = f2bf(v);
    } else if (t < n1) {
        int idx = t - n0;
        int e = idx & 7, lane = (idx >> 3) & 63, cs = idx >> 9;
        int ct = cs / 12, ks = cs - ct*12;
        int k = ks*32 + ((lane>>4)<<3) + e, col = ct*16 + (lane & 15);
        float v = (k < 192) ? Wfused[k*576 + col] : W_hh[col*192 + (k - 192)];
        Wr[idx] = f2bf(v);
    } else if (t < n2) {
        int idx = t - n1;
        int e = idx & 7, lane = (idx >> 3) & 63, cs = idx >> 9;
        int ct = cs / 12, ks = cs - ct*12;
        int k = ks*32 + ((lane>>4)<<3) + e, col = ct*16 + (lane & 15);
        float v = (k < 192) ? Wfused[k*576 + 192 + col] : W_hh[(192 + col)*192 + (k - 192)];
        Wz[idx] = f2bf(v);
    } else if (t < n3) {
        int idx = t - n2;
        int e = idx & 7, lane = (idx >> 3) & 63, cs = idx >> 9;
        int ct = cs / 6, ks = cs - ct*6;
        int k = ks*32 + ((lane>>4)<<3) + e, col = ct*16 + (lane & 15);
        Wni[idx] = f2bf(Wfused[k*576 + 384 + col]);
    } else if (t < n4) {
        int idx = t - n3;
        int e = idx & 7, lane = (idx >> 3) & 63, cs = idx >> 9;
        int ct = cs / 6, ks = cs - ct*6;
        int k = ks*32 + ((lane>>4)<<3) + e, col = ct*16 + (lane & 15);
        Wnh[idx] = f2bf(W_hh[(384 + col)*192 + k]);
    } else if (t < n5) {
        int idx = t - n4;
        int e = idx & 7, lane = (idx >> 3) & 63, ks = idx >> 9;
        int k = ks*32 + ((lane>>4)<<3) + e, col = lane & 15;
        Woutb[idx] = (col < 9) ? f2bf(W_out[k*9 + col]) : (ushort_t)0;
    } else if (t < n6) {
        int n = t - n5;
        float s = 0.f;
        for (int m = 0; m < 192; m++) s += b_m2[m] * W_ih[n*192 + m];
        bias_f[n] = 20.f * s + b_ih[n];
    }
}

// ---------------------------------------------------------------------------
// Monolithic RRN kernel: one workgroup per graph, all 16 steps LDS-resident.
// LDS map (163200 B total, <=163840):
//   hf    f32  [81][192] @0       (hc scratch, HFI swizzle)
//   AB    bf16 [81][384] @62208   (A|B proj; Rb overlays low half, HBI)
//   spart float2[324]    @94976   (LN partial sums; overlays dead AB space)
//   hb    bf16 [81][192] @124416  (h state, HBI swizzle)
//   ssum/ssq f32[96]     @155520/155904
//   bm1s/gns/bens f32[192] @156288/157056/157824
//   biasf_s/bhh_s f32[576] @158592/160896
// ---------------------------------------------------------------------------
__global__ __launch_bounds__(512, 2)
void k_main(const float* __restrict__ x, const float* __restrict__ W_in,
            const float* __restrict__ b_in, const float* __restrict__ g_in,
            const float* __restrict__ be_in, const float* __restrict__ pos,
            const float* __restrict__ b_m1, const float* __restrict__ g_n,
            const float* __restrict__ be_n, const float* __restrict__ b_hh,
            const float* __restrict__ b_out,
            const ushort_t* __restrict__ Wm1b, const ushort_t* __restrict__ Wr,
            const ushort_t* __restrict__ Wz, const ushort_t* __restrict__ Wni,
            const ushort_t* __restrict__ Wnh, const ushort_t* __restrict__ Woutb,
            const float* __restrict__ bias_f,
            float* __restrict__ out_all, float* __restrict__ out_last)
{
    extern __shared__ char smem[];
    float*    hf    = (float*)(smem);
    ushort_t* AB    = (ushort_t*)(smem + 62208);
    float2*   spart = (float2*)(smem + 94976);
    ushort_t* hb    = (ushort_t*)(smem + 124416);
    float* ssum   = (float*)(smem + 155520);
    float* ssq    = (float*)(smem + 155904);
    float* bm1s   = (float*)(smem + 156288);
    float* gns    = (float*)(smem + 157056);
    float* bens   = (float*)(smem + 157824);
    float* biasfs = (float*)(smem + 158592);
    float* bhhs   = (float*)(smem + 160896);

    const int tid = threadIdx.x;
    const int lane = tid & 63, wave = tid >> 6;
    const int l15 = lane & 15, q4 = (lane >> 4) << 2;
    const int g = blockIdx.x;

    if (tid < 192) { bm1s[tid] = b_m1[tid]; gns[tid] = g_n[tid]; bens[tid] = be_n[tid]; }
    for (int e = tid; e < 576; e += 512) { biasfs[e] = bias_f[e]; bhhs[e] = b_hh[e]; }

    // Phase-A weights: loop-invariant, hold in registers for the whole kernel
    bf16x8 wb[3][6];
#pragma unroll
    for (int c = 0; c < 3; c++)
#pragma unroll
        for (int ks = 0; ks < 6; ks++)
            wb[c][ks] = wfragN(Wm1b, wave*3 + c, 6, ks, lane);

    // ---------------- h0 = LN(x@W_in + b_in)*g+be + pos ----------------
    {
        float* xs = (float*)AB;
        for (int e = tid; e < 810; e += 512) xs[e] = x[(size_t)g*810 + e];
        __syncthreads();
        for (int e = tid; e < 15552; e += 512) {
            int n = e / 192, j = e - n*192;
            float v = b_in[j];
#pragma unroll
            for (int k = 0; k < 10; k++) v += xs[n*10 + k] * W_in[k*192 + j];
            hf[HFI(n, j)] = v;
        }
        __syncthreads();
        if (tid < 324) {
            int row = tid >> 2, part = tid & 3;
            float s = 0.f, q = 0.f;
#pragma unroll
            for (int i = 0; i < 12; i++) {
                int c = part*48 + i*4;
                float4 v = *(float4*)&hf[HFI(row, c)];
                s += v.x + v.y + v.z + v.w;
                q += v.x*v.x + v.y*v.y + v.z*v.z + v.w*v.w;
            }
            spart[tid] = make_float2(s, q);
        }
        __syncthreads();
        if (tid < 81) {
            float2 p0 = spart[tid*4], p1 = spart[tid*4+1], p2 = spart[tid*4+2], p3 = spart[tid*4+3];
            float s = p0.x+p1.x+p2.x+p3.x, q = p0.y+p1.y+p2.y+p3.y;
            float m = s * (1.f/192.f);
            float var = q * (1.f/192.f) - m*m;
            ssum[tid] = m; ssq[tid] = rsqrtf(var + 1e-5f);
        }
        __syncthreads();
        for (int e = tid; e < 15552; e += 512) {
            int n = e / 192, j = e - n*192;
            float v = hf[HFI(n, j)];
            v = (v - ssum[n]) * ssq[n] * g_in[j] + be_in[j] + pos[n*192 + j];
            hb[HBI(n, j)] = f2bf(v);
        }
        __syncthreads();
    }

    for (int t = 0; t < NSTEPS; t++) {
        // ===== Phase A: [A|B] = h @ Wm1comb  (b_m1 folded into B half) =====
#pragma unroll
        for (int rt = 0; rt < 6; rt++) {
            bf16x8 ha[6];
#pragma unroll
            for (int ks = 0; ks < 6; ks++) ha[ks] = ldsfrag(hb, rt, ks, lane);
#pragma unroll
            for (int c = 0; c < 3; c++) {
                f32x4 acc = {0.f, 0.f, 0.f, 0.f};
#pragma unroll
                for (int ks = 0; ks < 6; ks++)
                    acc = __builtin_amdgcn_mfma_f32_16x16x32_bf16(ha[ks], wb[c][ks], acc, 0, 0, 0);
                int col = (wave*3 + c)*16 + l15;
                float addb = (col >= 192) ? bm1s[col - 192] : 0.f;
#pragma unroll
                for (int i2 = 0; i2 < 4; i2++) {
                    int row = rt*16 + q4 + i2;
                    if (row < 81) AB[ABI(row, col)] = f2bf(acc[i2] + addb);
                }
            }
        }
        __syncthreads();   // SYNC1

        // ===== Phase B: R[d] = sum_{s in nbr(d)} relu(A[s] + B[d]) =====
        float racc[4][8];
#pragma unroll
        for (int it = 0; it < 4; it++) {
            int e = tid + 512*it;
            if (e < 1944) {
                int d = e / 24, j8 = e - d*24;
                int j0 = j8 * 8;
                float bsum[8], r8[8] = {0,0,0,0,0,0,0,0};
                us8 bu = *(const us8*)&AB[ABI(d, 192 + j0)];
#pragma unroll
                for (int i = 0; i < 8; i++) bsum[i] = bf2f(bu[i]);
                int rr = d / 9, cc = d - rr*9;
                int rb0 = (rr/3)*3, cb0 = (cc/3)*3;
#pragma unroll
                for (int c2 = 0; c2 < 9; c2++) {
                    if (c2 == cc) continue;
                    us8 au = *(const us8*)&AB[ABI(rr*9 + c2, j0)];
#pragma unroll
                    for (int i = 0; i < 8; i++) r8[i] += fmaxf(bf2f(au[i]) + bsum[i], 0.f);
                }
#pragma unroll
                for (int r2 = 0; r2 < 9; r2++) {
                    if (r2 == rr) continue;
                    us8 au = *(const us8*)&AB[ABI(r2*9 + cc, j0)];
#pragma unroll
                    for (int i = 0; i < 8; i++) r8[i] += fmaxf(bf2f(au[i]) + bsum[i], 0.f);
                }
#pragma unroll
                for (int r2 = 0; r2 < 3; r2++) {
                    int rrr = rb0 + r2;
                    if (rrr == rr) continue;
#pragma unroll
                    for (int c2 = 0; c2 < 3; c2++) {
                        int ccc = cb0 + c2;
                        if (ccc == cc) continue;
                        us8 au = *(const us8*)&AB[ABI(rrr*9 + ccc, j0)];
#pragma unroll
                        for (int i = 0; i < 8; i++) r8[i] += fmaxf(bf2f(au[i]) + bsum[i], 0.f);
                    }
                }
#pragma unroll
                for (int i = 0; i < 8; i++) racc[it][i] = r8[i];
            }
        }
        __syncthreads();   // SYNC2
#pragma unroll
        for (int it = 0; it < 4; it++) {
            int e = tid + 512*it;
            if (e < 1944) {
                int d = e / 24, j8 = e - d*24;
                int j0 = j8 * 8;
                us8 w;
#pragma unroll
                for (int i = 0; i < 8; i++) w[i] = f2bf(racc[it][i]);
                *(us8*)&AB[HBI(d, j0)] = w;   // Rb overlays AB, HBI geometry
            }
        }
        __syncthreads();   // SYNC3

        // ===== Phase C: column-sliced 4-gate GEMM (K=384 via [R|h]) + GRU ===
#pragma unroll
        for (int rep = 0; rep < 2; rep++) {
            int ct = wave + rep*8;
            if (ct < 12) {
                f32x4 accr[6] = {}, accz[6] = {}, accni[6] = {}, accnh[6] = {};
#pragma unroll
                for (int ks = 0; ks < 12; ks++) {
                    bf16x8 wfr = wfragN(Wr, ct, 12, ks, lane);
                    bf16x8 wfz = wfragN(Wz, ct, 12, ks, lane);
                    bf16x8 wfn = (ks < 6) ? wfragN(Wni, ct, 6, ks, lane)
                                          : wfragN(Wnh, ct, 6, ks - 6, lane);
#pragma unroll
                    for (int rt = 0; rt < 6; rt++) {
                        bf16x8 af = (ks < 6) ? ldsfrag(AB, rt, ks, lane)
                                             : ldsfrag(hb, rt, ks - 6, lane);
                        accr[rt] = __builtin_amdgcn_mfma_f32_16x16x32_bf16(af, wfr, accr[rt], 0,0,0);
                        accz[rt] = __builtin_amdgcn_mfma_f32_16x16x32_bf16(af, wfz, accz[rt], 0,0,0);
                        if (ks < 6)
                            accni[rt] = __builtin_amdgcn_mfma_f32_16x16x32_bf16(af, wfn, accni[rt], 0,0,0);
                        else
                            accnh[rt] = __builtin_amdgcn_mfma_f32_16x16x32_bf16(af, wfn, accnh[rt], 0,0,0);
                    }
                }
                int col = ct*16 + l15;
                float br  = biasfs[col]       + bhhs[col];
                float bz  = biasfs[col + 192] + bhhs[col + 192];
                float bni = biasfs[col + 384];
                float bnh = bhhs[col + 384];
#pragma unroll
                for (int rt = 0; rt < 6; rt++) {
#pragma unroll
                    for (int i2 = 0; i2 < 4; i2++) {
                        int row = rt*16 + q4 + i2;
                        if (row < 81) {
                            float rg = 1.f/(1.f + __expf(-(accr[rt][i2] + br)));
                            float zg = 1.f/(1.f + __expf(-(accz[rt][i2] + bz)));
                            float e2 = __expf(2.f*(accni[rt][i2] + bni + rg*(accnh[rt][i2] + bnh)));
                            float ng = 1.f - 2.f/(e2 + 1.f);
                            float hv = bf2f(hb[HBI(row, col)]);
                            hf[HFI(row, col)] = (1.f - zg)*ng + zg*hv;
                        }
                    }
                }
            }
        }
        __syncthreads();   // SYNC4
        // ===== LN stats (partial sums, no atomics) =====
        if (tid < 324) {
            int row = tid >> 2, part = tid & 3;
            float s = 0.f, q = 0.f;
#pragma unroll
            for (int i = 0; i < 12; i++) {
                int c = part*48 + i*4;
                float4 v = *(float4*)&hf[HFI(row, c)];
                s += v.x + v.y + v.z + v.w;
                q += v.x*v.x + v.y*v.y + v.z*v.z + v.w*v.w;
            }
            spart[tid] = make_float2(s, q);
        }
        __syncthreads();   // SYNC5
        if (tid < 81) {
            float2 p0 = spart[tid*4], p1 = spart[tid*4+1], p2 = spart[tid*4+2], p3 = spart[tid*4+3];
            float s = p0.x+p1.x+p2.x+p3.x, q = p0.y+p1.y+p2.y+p3.y;
            float m = s * (1.f/192.f);
            float var = q * (1.f/192.f) - m*m;
            ssum[tid] = m; ssq[tid] = rsqrtf(var + 1e-5f);
        }
        __syncthreads();   // SYNC6
        // ===== Phase D: LayerNorm -> new h (bf16) =====
        for (int e = tid; e < 15552; e += 512) {
            int n = e / 192, j = e - n*192;
            float hc = hf[HFI(n, j)];
            float hn2 = (hc - ssum[n]) * ssq[n] * gns[j] + bens[j];
            hb[HBI(n, j)] = f2bf(hn2);
        }
        __syncthreads();   // SYNC7
        // ===== Phase E: logits = h @ W_out + b_out =====
        if (wave < 6) {
            int rt = wave;
            f32x4 acc = {0.f, 0.f, 0.f, 0.f};
#pragma unroll
            for (int ks = 0; ks < 6; ks++) {
                bf16x8 ha = ldsfrag(hb, rt, ks, lane);
                acc = __builtin_amdgcn_mfma_f32_16x16x32_bf16(ha, wfragN(Woutb, 0, 6, ks, lane), acc, 0,0,0);
            }
            if (l15 < 9) {
                float bo = b_out[l15];
#pragma unroll
                for (int i2 = 0; i2 < 4; i2++) {
                    int row = rt*16 + q4 + i2;
                    if (row < 81) {
                        float v = acc[i2] + bo;
                        out_all[((size_t)t*NNODES + (size_t)g*81 + row)*9 + l15] = v;
                        if (t == NSTEPS-1)
                            out_last[((size_t)g*81 + row)*9 + l15] = v;
                    }
                }
            }
        }
    }
}

// ---------------------------------------------------------------------------
extern "C" void kernel_launch(void* const* d_in, const int* in_sizes, int n_in,
                              void* d_out, int out_size, void* d_ws, size_t ws_size,
                              hipStream_t stream) {
    const float* x     = (const float*)d_in[0];
    const float* W_in  = (const float*)d_in[2];
    const float* b_in  = (const float*)d_in[3];
    const float* g_in  = (const float*)d_in[4];
    const float* be_in = (const float*)d_in[5];
    const float* pos   = (const float*)d_in[6];
    const float* W_m1  = (const float*)d_in[7];
    const float* b_m1  = (const float*)d_in[8];
    const float* W_m2  = (const float*)d_in[9];
    const float* b_m2  = (const float*)d_in[10];
    const float* W_ih  = (const float*)d_in[11];
    const float* W_hh  = (const float*)d_in[12];
    const float* b_ih  = (const float*)d_in[13];
    const float* b_hh  = (const float*)d_in[14];
    const float* g_n   = (const float*)d_in[15];
    const float* be_n  = (const float*)d_in[16];
    const float* W_out = (const float*)d_in[17];
    const float* b_out = (const float*)d_in[18];

    char* ws = (char*)d_ws;
    float*    Wfused = (float*)ws;                   // 192*576*4 = 442368
    ushort_t* Wm1b   = (ushort_t*)(ws + 442368);     // 147456
    ushort_t* Wr     = (ushort_t*)(ws + 589824);     // 147456
    ushort_t* Wz     = (ushort_t*)(ws + 737280);     // 147456
    ushort_t* Wni    = (ushort_t*)(ws + 884736);     // 73728
    ushort_t* Wnh    = (ushort_t*)(ws + 958464);     // 73728
    ushort_t* Woutb  = (ushort_t*)(ws + 1032192);    // 6144
    float*    bias_f = (float*)(ws + 1038336);       // 2304

    float* out_last = (float*)d_out;                 // (5184, 9)
    float* out_all  = (float*)d_out + NNODES*9;      // (16, 5184, 9)

    // Wfused = W_m2 @ W_ih^T   (192 x 576, fp32)
    k_gemm<true><<<dim3(3, 9), 256, 0, stream>>>(W_m2, W_ih, nullptr, 0.f, Wfused, 576);
    // weight -> bf16 fragment layouts + fused bias
    k_prep<<<(298560 + 255)/256, 256, 0, stream>>>(W_m1, Wfused, W_hh, W_out, W_ih, b_m2, b_ih,
                                                   Wm1b, Wr, Wz, Wni, Wnh, Woutb, bias_f);

    const int LDS_BYTES = 163200;
    hipFuncSetAttribute(reinterpret_cast<const void*>(k_main),
                        hipFuncAttributeMaxDynamicSharedMemorySize, LDS_BYTES);
    k_main<<<64, 512, LDS_BYTES, stream>>>(x, W_in, b_in, g_in, be_in, pos, b_m1, g_n, be_n,
                                           b_hh, b_out, Wm1b, Wr, Wz, Wni, Wnh, Woutb, bias_f,
                                           out_all, out_last);
}